// Round 15
// baseline (77.121 us; speedup 1.0000x reference)
//
#include <hip/hip_runtime.h>
#include <hip/hip_bf16.h>

typedef __attribute__((ext_vector_type(8))) short short8;
typedef __attribute__((ext_vector_type(4))) float f32x4;
typedef __attribute__((ext_vector_type(2))) float f32x2;

// Problem constants
constexpr int DIM_ = 1024;
constexpr int H_   = 16;
constexpr int D_   = 64;
constexpr int HID_ = 1024;
constexpr int N_   = 2;
constexpr int T_   = 1024;
constexpr int MTOT = N_ * T_;   // 2048

// scan chunking
constexpr int LC = 32;           // chunk length
constexpr int NC = T_ / LC;      // 32 chunks
constexpr int NHEAD = N_ * H_;   // 32

__device__ __forceinline__ unsigned short f2bf(float f) {
    __hip_bfloat16 h = __float2bfloat16(f);
    unsigned short u; __builtin_memcpy(&u, &h, 2); return u;
}
__device__ __forceinline__ float bf2f(unsigned short u) {
    unsigned int b = ((unsigned int)u) << 16;
    float f; __builtin_memcpy(&f, &b, 4); return f;
}

__device__ __forceinline__ void gload16(const void* g, void* l) {
    __builtin_amdgcn_global_load_lds(
        (const __attribute__((address_space(1))) void*)g,
        (__attribute__((address_space(3))) void*)l, 16, 0, 0);
}

// ---------------------------------------------------------------------------
// fp32 -> bf16 conversion for x, key_w, vq_w, out_w. 8 elems/thread.
// ---------------------------------------------------------------------------
__global__ __launch_bounds__(256) void cvt_all(
    const float* __restrict__ x,  const float* __restrict__ kw,
    const float* __restrict__ vq, const float* __restrict__ ow,
    unsigned short* __restrict__ Xb, unsigned short* __restrict__ Wb,
    unsigned short* __restrict__ OWb)
{
    int b = blockIdx.x;
    const float* src; unsigned short* dst; int off;
    if      (b < 1024) { src = x;  dst = Xb;                 off = b; }
    else if (b < 1536) { src = kw; dst = Wb;                 off = b - 1024; }
    else if (b < 2560) { src = vq; dst = Wb + 1024 * 1024;   off = b - 1536; }
    else               { src = ow; dst = OWb;                off = b - 2560; }
    size_t i = ((size_t)off * 256 + threadIdx.x) * 8;
    float4 v0 = *(const float4*)&src[i];
    float4 v1 = *(const float4*)&src[i + 4];
    short8 o;
    o[0] = (short)f2bf(v0.x); o[1] = (short)f2bf(v0.y);
    o[2] = (short)f2bf(v0.z); o[3] = (short)f2bf(v0.w);
    o[4] = (short)f2bf(v1.x); o[5] = (short)f2bf(v1.y);
    o[6] = (short)f2bf(v1.z); o[7] = (short)f2bf(v1.w);
    *(short8*)&dst[i] = o;
}

// ---------------------------------------------------------------------------
// gemm_qkv: 64x128 tile, 4x BK=32 buffer sets per barrier pair (K=128/iter).
// Grid 768 = 3/CU, LDS 48 KB x 3 = 144 <= 160. Linear gload_lds dest +
// inverse-swizzled global source + swizzled ds_read (rule #21), 2-way free.
// ---------------------------------------------------------------------------
__global__ __launch_bounds__(256) void gemm_qkv_mfma(
    const unsigned short* __restrict__ Ab,   // Xb [2048][1024]
    const unsigned short* __restrict__ Bb,   // Wb [3072][1024]
    const float* __restrict__ key_b,
    unsigned short* __restrict__ Gb,         // g = 1 - sigmoid(z), bf16
    unsigned short* __restrict__ Vb,
    unsigned short* __restrict__ Qb)
{
    __shared__ unsigned short As[4][64 * 32];
    __shared__ unsigned short Bs[4][128 * 32];
    const int tid = threadIdx.x, w = tid >> 6, lane = tid & 63;
    const int wm = w >> 1, wn = w & 1;
    const int M0 = blockIdx.y * 64, N0 = blockIdx.x * 128;
    const int srow = tid >> 2;
    const int kA = (((tid & 3) ^ ((srow >> 1) & 3)) * 8);
    const unsigned short* gA  = Ab + (size_t)(M0 + srow) * DIM_ + kA;
    const unsigned short* gB0 = Bb + (size_t)(N0 + srow) * DIM_ + kA;
    const unsigned short* gB1 = Bb + (size_t)(N0 + 64 + srow) * DIM_ + kA;
    const int fr = lane & 15, fc = lane >> 4;
    const int p  = fc ^ ((fr >> 1) & 3);
    const int aoff = (wm * 32 + fr) * 64 + p * 16;
    const int boff = (wn * 64 + fr) * 64 + p * 16;
    f32x4 acc[2][4] = {};

    for (int k0 = 0; k0 < DIM_; k0 += 128) {
        __syncthreads();
        #pragma unroll
        for (int s = 0; s < 4; ++s) {
            gload16(gA  + k0 + s * 32, (char*)As[s] + w * 1024);
            gload16(gB0 + k0 + s * 32, (char*)Bs[s] + w * 1024);
            gload16(gB1 + k0 + s * 32, (char*)Bs[s] + w * 1024 + 4096);
        }
        __syncthreads();
        #pragma unroll
        for (int s = 0; s < 4; ++s) {
            short8 a4[2], b4[4];
            #pragma unroll
            for (int i = 0; i < 2; ++i)
                a4[i] = *(const short8*)((const char*)As[s] + aoff + i * 1024);
            #pragma unroll
            for (int i = 0; i < 4; ++i)
                b4[i] = *(const short8*)((const char*)Bs[s] + boff + i * 1024);
            #pragma unroll
            for (int mi = 0; mi < 2; ++mi)
                #pragma unroll
                for (int ni = 0; ni < 4; ++ni)
                    acc[mi][ni] = __builtin_amdgcn_mfma_f32_16x16x32_bf16(
                        a4[mi], b4[ni], acc[mi][ni], 0, 0, 0);
        }
    }

    const int cm = M0 + wm * 32 + fc * 4;
    const int cn = N0 + wn * 64 + fr;
    if (N0 < HID_) {
        #pragma unroll
        for (int ni = 0; ni < 4; ++ni) {
            float bias = key_b[cn + ni * 16];
            #pragma unroll
            for (int mi = 0; mi < 2; ++mi)
                #pragma unroll
                for (int r = 0; r < 4; ++r) {
                    float vv = acc[mi][ni][r] + bias;
                    Gb[(size_t)(cm + mi * 16 + r) * HID_ + cn + ni * 16] =
                        f2bf(1.f / (1.f + __expf(vv)));
                }
        }
    } else if (N0 < 2 * HID_) {
        #pragma unroll
        for (int ni = 0; ni < 4; ++ni)
            #pragma unroll
            for (int mi = 0; mi < 2; ++mi)
                #pragma unroll
                for (int r = 0; r < 4; ++r)
                    Vb[(size_t)(cm + mi * 16 + r) * HID_ + cn + ni * 16 - HID_] =
                        f2bf(acc[mi][ni][r]);
    } else {
        #pragma unroll
        for (int ni = 0; ni < 4; ++ni)
            #pragma unroll
            for (int mi = 0; mi < 2; ++mi)
                #pragma unroll
                for (int r = 0; r < 4; ++r)
                    Qb[(size_t)(cm + mi * 16 + r) * HID_ + cn + ni * 16 - 2 * HID_] =
                        f2bf(acc[mi][ni][r]);
    }
}

// ---------------------------------------------------------------------------
// gemm_out: 64x64 tile, 8x BK=32 buffer sets (K=256/iter, 4 barrier-pairs).
// Grid (16,32) = 512 = 2/CU; LDS 64 KB x 2 = 128 <= 160 (occupancy unchanged,
// barrier count halved again — same R7/R14 axis).
// ---------------------------------------------------------------------------
__global__ __launch_bounds__(256) void gemm_out_mfma(
    const unsigned short* __restrict__ Ab,   // Hb bf16 [2048][1024]
    const unsigned short* __restrict__ Bb,   // OWb bf16 [1024][1024]
    const float* __restrict__ out_b,
    float* __restrict__ Out)
{
    __shared__ unsigned short As[8][64 * 32];
    __shared__ unsigned short Bs[8][64 * 32];
    const int tid = threadIdx.x, w = tid >> 6, lane = tid & 63;
    const int wm = w >> 1, wn = w & 1;
    const int M0 = blockIdx.y * 64, N0 = blockIdx.x * 64;
    const int srow = tid >> 2;
    const int kA = (((tid & 3) ^ ((srow >> 1) & 3)) * 8);
    const unsigned short* gA = Ab + (size_t)(M0 + srow) * DIM_ + kA;
    const unsigned short* gB = Bb + (size_t)(N0 + srow) * DIM_ + kA;
    const int fr = lane & 15, fc = lane >> 4;
    const int p  = fc ^ ((fr >> 1) & 3);
    const int aoff = (wm * 32 + fr) * 64 + p * 16;
    const int boff = (wn * 32 + fr) * 64 + p * 16;
    f32x4 acc[2][2] = {};

    for (int k0 = 0; k0 < DIM_; k0 += 256) {
        __syncthreads();
        #pragma unroll
        for (int s = 0; s < 8; ++s) {
            gload16(gA + k0 + s * 32, (char*)As[s] + w * 1024);
            gload16(gB + k0 + s * 32, (char*)Bs[s] + w * 1024);
        }
        __syncthreads();
        #pragma unroll
        for (int s = 0; s < 8; ++s) {
            short8 a4[2], b4[2];
            #pragma unroll
            for (int i = 0; i < 2; ++i) {
                a4[i] = *(const short8*)((const char*)As[s] + aoff + i * 1024);
                b4[i] = *(const short8*)((const char*)Bs[s] + boff + i * 1024);
            }
            #pragma unroll
            for (int mi = 0; mi < 2; ++mi)
                #pragma unroll
                for (int ni = 0; ni < 2; ++ni)
                    acc[mi][ni] = __builtin_amdgcn_mfma_f32_16x16x32_bf16(
                        a4[mi], b4[ni], acc[mi][ni], 0, 0, 0);
        }
    }

    const int cm = M0 + wm * 32 + fc * 4;
    const int cn = N0 + wn * 32 + fr;
    #pragma unroll
    for (int ni = 0; ni < 2; ++ni) {
        float bias = out_b[cn + ni * 16];
        #pragma unroll
        for (int mi = 0; mi < 2; ++mi)
            #pragma unroll
            for (int r = 0; r < 4; ++r)
                Out[(size_t)(cm + mi * 16 + r) * DIM_ + cn + ni * 16] =
                    acc[mi][ni][r] + bias;
    }
}

// ---------------------------------------------------------------------------
// Scan phase 1 (only scalar pass): per (head, chunk of 32):
//  - scan kv from ZERO state  -> h_intra (bf16 -> Hb)
//  - chunk-end state B_c      -> SbufB [head][c][e][d] bf16
//  - chunk decay product P_c  -> Pbuf  [head][c][d]    fp32
//  - qa[t,d] = q[t,d]*cumprod_k (incl) -> QAb [head][c][t][d] bf16
// Block: 256 thr = 4 waves; wave w owns d in [w*16,w*16+16); lane = e.
// Hot loop in f32x2 packed form: __builtin_elementwise_fma on float2 emits
// v_pk_fma_f32 (VOP3P) — ~1.5 VALU/elem vs 3 scalar.
// ---------------------------------------------------------------------------
__global__ __launch_bounds__(256) void scan_phase1(
    const unsigned short* __restrict__ Gb,
    const unsigned short* __restrict__ Vb,
    const unsigned short* __restrict__ Qb,
    unsigned short* __restrict__ SbufB,
    float* __restrict__ Pbuf,
    unsigned short* __restrict__ QAb,
    unsigned short* __restrict__ Hb)
{
    __shared__ float sg[LC][64];                 // 8 KB (holds g = 1-k)
    __shared__ float sv[LC][64];                 // 8 KB
    __shared__ float sq[LC][64];                 // 8 KB
    __shared__ unsigned short hp[4][16][64];     // 8 KB
    __shared__ unsigned short qs[LC][64];        // 4 KB

    const int tid  = threadIdx.x;
    const int w    = tid >> 6;
    const int lane = tid & 63;
    const int c    = blockIdx.x & (NC - 1);
    const int head = blockIdx.x >> 5;
    const int n = head >> 4, h = head & 15;
    const size_t base = ((size_t)n * T_) * HID_ + (size_t)h * 64;

    // stage the whole chunk: g/v/q all bf16 short8
    {
        int f = tid * 8;
        int tl = f >> 6, d = f & 63;
        size_t g = base + (size_t)(c * LC + tl) * HID_ + d;
        short8 g8 = *(const short8*)&Gb[g];
        short8 v8 = *(const short8*)&Vb[g];
        short8 q8 = *(const short8*)&Qb[g];
        #pragma unroll
        for (int j = 0; j < 8; ++j) {
            sg[tl][d + j] = bf2f((unsigned short)g8[j]);
            sv[tl][d + j] = bf2f((unsigned short)v8[j]);
            sq[tl][d + j] = bf2f((unsigned short)q8[j]);
        }
    }
    __syncthreads();

    const int dq = w * 16 + (lane & 15);   // d this lane tracks for qa/P
    f32x2 kv2[8];
    #pragma unroll
    for (int i = 0; i < 8; ++i) kv2[i] = (f32x2){0.f, 0.f};
    float pq = 1.f;

    #pragma unroll
    for (int half = 0; half < 2; ++half) {
        for (int tl2 = 0; tl2 < 16; ++tl2) {
            const int tl = half * 16 + tl2;
            f32x2 part2 = {0.f, 0.f};
            float v = sv[tl][lane];
            f32x2 v2 = {v, v};
            #pragma unroll
            for (int i4 = 0; i4 < 4; ++i4) {
                float4 g4 = *(const float4*)&sg[tl][w * 16 + i4 * 4];
                float4 q4 = *(const float4*)&sq[tl][w * 16 + i4 * 4];
                f32x2 g2[2] = { {g4.x, g4.y}, {g4.z, g4.w} };
                f32x2 q2[2] = { {q4.x, q4.y}, {q4.z, q4.w} };
                #pragma unroll
                for (int j = 0; j < 2; ++j) {
                    int i = i4 * 2 + j;
                    kv2[i] = __builtin_elementwise_fma(g2[j], v2 - kv2[i], kv2[i]);
                    part2  = __builtin_elementwise_fma(q2[j], kv2[i], part2);
                }
            }
            hp[w][tl2][lane] = f2bf(part2[0] + part2[1]);
            pq *= (1.f - sg[tl][dq]);
            if (lane < 16) qs[tl][dq] = f2bf(sq[tl][dq] * pq);
        }
        __syncthreads();
        #pragma unroll
        for (int i = 0; i < 16 * 64 / 256; ++i) {
            int idx = tid + i * 256;
            int tl2 = idx >> 6, e = idx & 63;
            float s = bf2f(hp[0][tl2][e]) + bf2f(hp[1][tl2][e]) +
                      bf2f(hp[2][tl2][e]) + bf2f(hp[3][tl2][e]);
            Hb[base + (size_t)(c * LC + half * 16 + tl2) * HID_ + e] = f2bf(s);
        }
        __syncthreads();
    }

    // B_c -> SbufB bf16 in [e][d] layout (kv element j = kv2[j>>1][j&1])
    const size_t sbase = (size_t)(head * NC + c) * (D_ * D_);
    #pragma unroll
    for (int i = 0; i < 4; ++i) {
        ushort4 o = { f2bf(kv2[i * 2][0]),     f2bf(kv2[i * 2][1]),
                      f2bf(kv2[i * 2 + 1][0]), f2bf(kv2[i * 2 + 1][1]) };
        *(ushort4*)&SbufB[sbase + (size_t)lane * D_ + w * 16 + i * 4] = o;
    }
    if (lane < 16) Pbuf[(size_t)(head * NC + c) * D_ + dq] = pq;
    const unsigned short* qsl = &qs[0][0];
    *(short8*)&QAb[(size_t)(head * NC + c) * (LC * 64) + tid * 8] =
        *(const short8*)&qsl[tid * 8];
}

// ---------------------------------------------------------------------------
// Scan phase 2: combine across chunks. grid = 32 heads x 16 e-groups (512 blocks).
// Each thread owns one (e,d) element. ALL chunk loads prefetched to registers
// (independent, pipelined) before the serial FMA chain.
// ---------------------------------------------------------------------------
__global__ __launch_bounds__(256) void scan_combine(
    const unsigned short* __restrict__ SbufB,
    const float* __restrict__ Pbuf,
    unsigned short* __restrict__ SInitB)
{
    const int tid  = threadIdx.x;
    const int head = blockIdx.x >> 4;
    const int e    = (blockIdx.x & 15) * 4 + (tid >> 6);
    const int d    = tid & 63;

    unsigned short Bv[NC];
    float Pv[NC];
    #pragma unroll
    for (int ci = 0; ci < NC; ++ci) {
        const size_t sidx = (size_t)(head * NC + ci) * (D_ * D_) + (size_t)e * D_ + d;
        Bv[ci] = SbufB[sidx];
        Pv[ci] = Pbuf[(size_t)(head * NC + ci) * D_ + d];
    }

    float S = 0.f;
    #pragma unroll
    for (int ci = 0; ci < NC; ++ci) {
        const size_t sidx = (size_t)(head * NC + ci) * (D_ * D_) + (size_t)e * D_ + d;
        SInitB[sidx] = f2bf(S);
        S = Pv[ci] * S + bf2f(Bv[ci]);
    }
}

// ---------------------------------------------------------------------------
// Scan phase 3 (MFMA): h[t,e] += sum_d qa[t,d] * S_init[e,d]  per (head,chunk).
// One wave per (head,c); c==0 waves exit (S_init(0)=0).
// ---------------------------------------------------------------------------
__global__ __launch_bounds__(256) void scan_inter_mfma(
    const unsigned short* __restrict__ QAb,
    const unsigned short* __restrict__ SInitB,
    unsigned short* __restrict__ Hb)
{
    const int tid = threadIdx.x, w = tid >> 6, lane = tid & 63;
    const int wid  = blockIdx.x * 4 + w;      // 0..1023
    const int head = wid >> 5, c = wid & 31;
    if (c == 0) return;                       // wave-uniform: zero contribution
    const int n = head >> 4, h = head & 15;
    const int fr = lane & 15, fc = lane >> 4;

    const unsigned short* qa = QAb + (size_t)(head * NC + c) * (LC * 64);
    const unsigned short* sb = SInitB + (size_t)(head * NC + c) * (D_ * D_);

    short8 a[2][2], b[4][2];
    #pragma unroll
    for (int mi = 0; mi < 2; ++mi)
        #pragma unroll
        for (int ks = 0; ks < 2; ++ks)
            a[mi][ks] = *(const short8*)&qa[(mi * 16 + fr) * 64 + fc * 8 + ks * 32];
    #pragma unroll
    for (int ni = 0; ni < 4; ++ni)
        #pragma unroll
        for (int ks = 0; ks < 2; ++ks)
            b[ni][ks] = *(const short8*)&sb[(ni * 16 + fr) * 64 + fc * 8 + ks * 32];

    f32x4 acc[2][4] = {};
    #pragma unroll
    for (int mi = 0; mi < 2; ++mi)
        #pragma unroll
        for (int ni = 0; ni < 4; ++ni)
            #pragma unroll
            for (int ks = 0; ks < 2; ++ks)
                acc[mi][ni] = __builtin_amdgcn_mfma_f32_16x16x32_bf16(
                    a[mi][ks], b[ni][ks], acc[mi][ni], 0, 0, 0);

    #pragma unroll
    for (int mi = 0; mi < 2; ++mi)
        #pragma unroll
        for (int ni = 0; ni < 4; ++ni)
            #pragma unroll
            for (int r = 0; r < 4; ++r) {
                int t = c * LC + mi * 16 + fc * 4 + r;
                size_t g = ((size_t)n * T_ + t) * HID_ + h * 64 + ni * 16 + fr;
                Hb[g] = f2bf(bf2f(Hb[g]) + acc[mi][ni][r]);
            }
}

// ---------------------------------------------------------------------------
extern "C" void kernel_launch(void* const* d_in, const int* in_sizes, int n_in,
                              void* d_out, int out_size, void* d_ws, size_t ws_size,
                              hipStream_t stream)
{
    const float* x     = (const float*)d_in[0];
    const float* key_w = (const float*)d_in[1];
    const float* key_b = (const float*)d_in[2];
    const float* vq_w  = (const float*)d_in[3];
    const float* out_w = (const float*)d_in[4];
    const float* out_b = (const float*)d_in[5];
    float* out = (float*)d_out;

    const size_t MH = (size_t)MTOT * HID_;   // 2M elements
    unsigned short* Gb    = (unsigned short*)d_ws;                   // 4 MB
    unsigned short* Vb16  = Gb + MH;                                 // 4 MB
    unsigned short* Qb16  = Vb16 + MH;                               // 4 MB
    unsigned short* SbufB = Qb16 + MH;                               // 8 MB
    unsigned short* SInitB = SbufB + (size_t)NHEAD * NC * D_ * D_;   // 8 MB
    float* Pbuf = (float*)(SInitB + (size_t)NHEAD * NC * D_ * D_);   // 256 KB
    unsigned short* QAb = (unsigned short*)(Pbuf + (size_t)NHEAD * NC * D_);  // 4 MB
    unsigned short* Xb  = QAb + (size_t)NHEAD * NC * LC * D_;        // 4 MB
    unsigned short* Wb  = Xb + MH;                                   // 6 MB
    unsigned short* OWb = Wb + 3 * 1024 * 1024;                      // 2 MB
    unsigned short* Hb  = OWb + 1024 * 1024;                         // 4 MB

    cvt_all<<<3072, 256, 0, stream>>>(x, key_w, vq_w, out_w, Xb, Wb, OWb);
    gemm_qkv_mfma<<<dim3(24, 32), 256, 0, stream>>>(Xb, Wb, key_b, Gb, Vb16, Qb16);
    scan_phase1<<<NHEAD * NC, 256, 0, stream>>>(Gb, Vb16, Qb16, SbufB, Pbuf, QAb, Hb);
    scan_combine<<<NHEAD * 16, 256, 0, stream>>>(SbufB, Pbuf, SInitB);
    scan_inter_mfma<<<NHEAD * NC / 4, 256, 0, stream>>>(QAb, SInitB, Hb);
    gemm_out_mfma<<<dim3(16, 32), 256, 0, stream>>>(Hb, OWb, out_b, out);
}

// Round 16
// 76.503 us; speedup vs baseline: 1.0081x; 1.0081x over previous
//
#include <hip/hip_runtime.h>
#include <hip/hip_bf16.h>

typedef __attribute__((ext_vector_type(8))) short short8;
typedef __attribute__((ext_vector_type(4))) float f32x4;
typedef __attribute__((ext_vector_type(2))) float f32x2;

// Problem constants
constexpr int DIM_ = 1024;
constexpr int H_   = 16;
constexpr int D_   = 64;
constexpr int HID_ = 1024;
constexpr int N_   = 2;
constexpr int T_   = 1024;
constexpr int MTOT = N_ * T_;   // 2048

// scan chunking
constexpr int LC = 32;           // chunk length
constexpr int NC = T_ / LC;      // 32 chunks
constexpr int NHEAD = N_ * H_;   // 32

__device__ __forceinline__ unsigned short f2bf(float f) {
    __hip_bfloat16 h = __float2bfloat16(f);
    unsigned short u; __builtin_memcpy(&u, &h, 2); return u;
}
__device__ __forceinline__ float bf2f(unsigned short u) {
    unsigned int b = ((unsigned int)u) << 16;
    float f; __builtin_memcpy(&f, &b, 4); return f;
}

__device__ __forceinline__ void gload16(const void* g, void* l) {
    __builtin_amdgcn_global_load_lds(
        (const __attribute__((address_space(1))) void*)g,
        (__attribute__((address_space(3))) void*)l, 16, 0, 0);
}

// ---------------------------------------------------------------------------
// fp32 -> bf16 conversion for x, key_w, vq_w, out_w. 8 elems/thread.
// ---------------------------------------------------------------------------
__global__ __launch_bounds__(256) void cvt_all(
    const float* __restrict__ x,  const float* __restrict__ kw,
    const float* __restrict__ vq, const float* __restrict__ ow,
    unsigned short* __restrict__ Xb, unsigned short* __restrict__ Wb,
    unsigned short* __restrict__ OWb)
{
    int b = blockIdx.x;
    const float* src; unsigned short* dst; int off;
    if      (b < 1024) { src = x;  dst = Xb;                 off = b; }
    else if (b < 1536) { src = kw; dst = Wb;                 off = b - 1024; }
    else if (b < 2560) { src = vq; dst = Wb + 1024 * 1024;   off = b - 1536; }
    else               { src = ow; dst = OWb;                off = b - 2560; }
    size_t i = ((size_t)off * 256 + threadIdx.x) * 8;
    float4 v0 = *(const float4*)&src[i];
    float4 v1 = *(const float4*)&src[i + 4];
    short8 o;
    o[0] = (short)f2bf(v0.x); o[1] = (short)f2bf(v0.y);
    o[2] = (short)f2bf(v0.z); o[3] = (short)f2bf(v0.w);
    o[4] = (short)f2bf(v1.x); o[5] = (short)f2bf(v1.y);
    o[6] = (short)f2bf(v1.z); o[7] = (short)f2bf(v1.w);
    *(short8*)&dst[i] = o;
}

// ---------------------------------------------------------------------------
// gemm_qkv: 64x128 tile, 4x BK=32 buffer sets per barrier pair (K=128/iter).
// Grid 768 = 3/CU, LDS 48 KB x 3 = 144 <= 160. Linear gload_lds dest +
// inverse-swizzled global source + swizzled ds_read (rule #21), 2-way free.
// ---------------------------------------------------------------------------
__global__ __launch_bounds__(256) void gemm_qkv_mfma(
    const unsigned short* __restrict__ Ab,   // Xb [2048][1024]
    const unsigned short* __restrict__ Bb,   // Wb [3072][1024]
    const float* __restrict__ key_b,
    unsigned short* __restrict__ Gb,         // g = 1 - sigmoid(z), bf16
    unsigned short* __restrict__ Vb,
    unsigned short* __restrict__ Qb)
{
    __shared__ unsigned short As[4][64 * 32];
    __shared__ unsigned short Bs[4][128 * 32];
    const int tid = threadIdx.x, w = tid >> 6, lane = tid & 63;
    const int wm = w >> 1, wn = w & 1;
    const int M0 = blockIdx.y * 64, N0 = blockIdx.x * 128;
    const int srow = tid >> 2;
    const int kA = (((tid & 3) ^ ((srow >> 1) & 3)) * 8);
    const unsigned short* gA  = Ab + (size_t)(M0 + srow) * DIM_ + kA;
    const unsigned short* gB0 = Bb + (size_t)(N0 + srow) * DIM_ + kA;
    const unsigned short* gB1 = Bb + (size_t)(N0 + 64 + srow) * DIM_ + kA;
    const int fr = lane & 15, fc = lane >> 4;
    const int p  = fc ^ ((fr >> 1) & 3);
    const int aoff = (wm * 32 + fr) * 64 + p * 16;
    const int boff = (wn * 64 + fr) * 64 + p * 16;
    f32x4 acc[2][4] = {};

    for (int k0 = 0; k0 < DIM_; k0 += 128) {
        __syncthreads();
        #pragma unroll
        for (int s = 0; s < 4; ++s) {
            gload16(gA  + k0 + s * 32, (char*)As[s] + w * 1024);
            gload16(gB0 + k0 + s * 32, (char*)Bs[s] + w * 1024);
            gload16(gB1 + k0 + s * 32, (char*)Bs[s] + w * 1024 + 4096);
        }
        __syncthreads();
        #pragma unroll
        for (int s = 0; s < 4; ++s) {
            short8 a4[2], b4[4];
            #pragma unroll
            for (int i = 0; i < 2; ++i)
                a4[i] = *(const short8*)((const char*)As[s] + aoff + i * 1024);
            #pragma unroll
            for (int i = 0; i < 4; ++i)
                b4[i] = *(const short8*)((const char*)Bs[s] + boff + i * 1024);
            #pragma unroll
            for (int mi = 0; mi < 2; ++mi)
                #pragma unroll
                for (int ni = 0; ni < 4; ++ni)
                    acc[mi][ni] = __builtin_amdgcn_mfma_f32_16x16x32_bf16(
                        a4[mi], b4[ni], acc[mi][ni], 0, 0, 0);
        }
    }

    const int cm = M0 + wm * 32 + fc * 4;
    const int cn = N0 + wn * 64 + fr;
    if (N0 < HID_) {
        #pragma unroll
        for (int ni = 0; ni < 4; ++ni) {
            float bias = key_b[cn + ni * 16];
            #pragma unroll
            for (int mi = 0; mi < 2; ++mi)
                #pragma unroll
                for (int r = 0; r < 4; ++r) {
                    float vv = acc[mi][ni][r] + bias;
                    Gb[(size_t)(cm + mi * 16 + r) * HID_ + cn + ni * 16] =
                        f2bf(1.f / (1.f + __expf(vv)));
                }
        }
    } else if (N0 < 2 * HID_) {
        #pragma unroll
        for (int ni = 0; ni < 4; ++ni)
            #pragma unroll
            for (int mi = 0; mi < 2; ++mi)
                #pragma unroll
                for (int r = 0; r < 4; ++r)
                    Vb[(size_t)(cm + mi * 16 + r) * HID_ + cn + ni * 16 - HID_] =
                        f2bf(acc[mi][ni][r]);
    } else {
        #pragma unroll
        for (int ni = 0; ni < 4; ++ni)
            #pragma unroll
            for (int mi = 0; mi < 2; ++mi)
                #pragma unroll
                for (int r = 0; r < 4; ++r)
                    Qb[(size_t)(cm + mi * 16 + r) * HID_ + cn + ni * 16 - 2 * HID_] =
                        f2bf(acc[mi][ni][r]);
    }
}

// ---------------------------------------------------------------------------
// gemm_out: 64x64 tile, 4x BK=32 buffer sets (K=128/iter) — R14-measured
// config (R15's 8-set/64KB variant was neutral-to-negative; reverted).
// Grid (16,32) = 512 = 2/CU; LDS 32 KB.
// ---------------------------------------------------------------------------
__global__ __launch_bounds__(256) void gemm_out_mfma(
    const unsigned short* __restrict__ Ab,   // Hb bf16 [2048][1024]
    const unsigned short* __restrict__ Bb,   // OWb bf16 [1024][1024]
    const float* __restrict__ out_b,
    float* __restrict__ Out)
{
    __shared__ unsigned short As[4][64 * 32];
    __shared__ unsigned short Bs[4][64 * 32];
    const int tid = threadIdx.x, w = tid >> 6, lane = tid & 63;
    const int wm = w >> 1, wn = w & 1;
    const int M0 = blockIdx.y * 64, N0 = blockIdx.x * 64;
    const int srow = tid >> 2;
    const int kA = (((tid & 3) ^ ((srow >> 1) & 3)) * 8);
    const unsigned short* gA = Ab + (size_t)(M0 + srow) * DIM_ + kA;
    const unsigned short* gB = Bb + (size_t)(N0 + srow) * DIM_ + kA;
    const int fr = lane & 15, fc = lane >> 4;
    const int p  = fc ^ ((fr >> 1) & 3);
    const int aoff = (wm * 32 + fr) * 64 + p * 16;
    const int boff = (wn * 32 + fr) * 64 + p * 16;
    f32x4 acc[2][2] = {};

    for (int k0 = 0; k0 < DIM_; k0 += 128) {
        __syncthreads();
        #pragma unroll
        for (int s = 0; s < 4; ++s) {
            gload16(gA + k0 + s * 32, (char*)As[s] + w * 1024);
            gload16(gB + k0 + s * 32, (char*)Bs[s] + w * 1024);
        }
        __syncthreads();
        #pragma unroll
        for (int s = 0; s < 4; ++s) {
            short8 a4[2], b4[2];
            #pragma unroll
            for (int i = 0; i < 2; ++i) {
                a4[i] = *(const short8*)((const char*)As[s] + aoff + i * 1024);
                b4[i] = *(const short8*)((const char*)Bs[s] + boff + i * 1024);
            }
            #pragma unroll
            for (int mi = 0; mi < 2; ++mi)
                #pragma unroll
                for (int ni = 0; ni < 2; ++ni)
                    acc[mi][ni] = __builtin_amdgcn_mfma_f32_16x16x32_bf16(
                        a4[mi], b4[ni], acc[mi][ni], 0, 0, 0);
        }
    }

    const int cm = M0 + wm * 32 + fc * 4;
    const int cn = N0 + wn * 32 + fr;
    #pragma unroll
    for (int ni = 0; ni < 2; ++ni) {
        float bias = out_b[cn + ni * 16];
        #pragma unroll
        for (int mi = 0; mi < 2; ++mi)
            #pragma unroll
            for (int r = 0; r < 4; ++r)
                Out[(size_t)(cm + mi * 16 + r) * DIM_ + cn + ni * 16] =
                    acc[mi][ni][r] + bias;
    }
}

// ---------------------------------------------------------------------------
// Scan phase 1 (only scalar pass): per (head, chunk of 32):
//  - scan kv from ZERO state  -> h_intra (bf16 -> Hb)
//  - chunk-end state B_c      -> SbufB [head][c][e][d] bf16
//  - chunk decay product P_c  -> Pbuf  [head][c][d]    fp32
//  - qa[t,d] = q[t,d]*cumprod_k (incl) -> QAb [head][c][t][d] bf16
// Block: 256 thr = 4 waves; wave w owns d in [w*16,w*16+16); lane = e.
// f32x2 packed FMA hot loop + FULLY UNROLLED t-loop: all LDS broadcast
// addresses become compile-time so the scheduler pipelines next-t reads
// under the current FMA chain (R15 null suggested LDS-issue latency, not
// VALU throughput, bounds this kernel).
// ---------------------------------------------------------------------------
__global__ __launch_bounds__(256) void scan_phase1(
    const unsigned short* __restrict__ Gb,
    const unsigned short* __restrict__ Vb,
    const unsigned short* __restrict__ Qb,
    unsigned short* __restrict__ SbufB,
    float* __restrict__ Pbuf,
    unsigned short* __restrict__ QAb,
    unsigned short* __restrict__ Hb)
{
    __shared__ float sg[LC][64];                 // 8 KB (holds g = 1-k)
    __shared__ float sv[LC][64];                 // 8 KB
    __shared__ float sq[LC][64];                 // 8 KB
    __shared__ unsigned short hp[4][16][64];     // 8 KB
    __shared__ unsigned short qs[LC][64];        // 4 KB

    const int tid  = threadIdx.x;
    const int w    = tid >> 6;
    const int lane = tid & 63;
    const int c    = blockIdx.x & (NC - 1);
    const int head = blockIdx.x >> 5;
    const int n = head >> 4, h = head & 15;
    const size_t base = ((size_t)n * T_) * HID_ + (size_t)h * 64;

    // stage the whole chunk: g/v/q all bf16 short8
    {
        int f = tid * 8;
        int tl = f >> 6, d = f & 63;
        size_t g = base + (size_t)(c * LC + tl) * HID_ + d;
        short8 g8 = *(const short8*)&Gb[g];
        short8 v8 = *(const short8*)&Vb[g];
        short8 q8 = *(const short8*)&Qb[g];
        #pragma unroll
        for (int j = 0; j < 8; ++j) {
            sg[tl][d + j] = bf2f((unsigned short)g8[j]);
            sv[tl][d + j] = bf2f((unsigned short)v8[j]);
            sq[tl][d + j] = bf2f((unsigned short)q8[j]);
        }
    }
    __syncthreads();

    const int dq = w * 16 + (lane & 15);   // d this lane tracks for qa/P
    f32x2 kv2[8];
    #pragma unroll
    for (int i = 0; i < 8; ++i) kv2[i] = (f32x2){0.f, 0.f};
    float pq = 1.f;

    #pragma unroll
    for (int half = 0; half < 2; ++half) {
        #pragma unroll
        for (int tl2 = 0; tl2 < 16; ++tl2) {
            const int tl = half * 16 + tl2;
            f32x2 part2 = {0.f, 0.f};
            float v = sv[tl][lane];
            f32x2 v2 = {v, v};
            #pragma unroll
            for (int i4 = 0; i4 < 4; ++i4) {
                float4 g4 = *(const float4*)&sg[tl][w * 16 + i4 * 4];
                float4 q4 = *(const float4*)&sq[tl][w * 16 + i4 * 4];
                f32x2 g2[2] = { {g4.x, g4.y}, {g4.z, g4.w} };
                f32x2 q2[2] = { {q4.x, q4.y}, {q4.z, q4.w} };
                #pragma unroll
                for (int j = 0; j < 2; ++j) {
                    int i = i4 * 2 + j;
                    kv2[i] = __builtin_elementwise_fma(g2[j], v2 - kv2[i], kv2[i]);
                    part2  = __builtin_elementwise_fma(q2[j], kv2[i], part2);
                }
            }
            hp[w][tl2][lane] = f2bf(part2[0] + part2[1]);
            pq *= (1.f - sg[tl][dq]);
            if (lane < 16) qs[tl][dq] = f2bf(sq[tl][dq] * pq);
        }
        __syncthreads();
        #pragma unroll
        for (int i = 0; i < 16 * 64 / 256; ++i) {
            int idx = tid + i * 256;
            int tl2 = idx >> 6, e = idx & 63;
            float s = bf2f(hp[0][tl2][e]) + bf2f(hp[1][tl2][e]) +
                      bf2f(hp[2][tl2][e]) + bf2f(hp[3][tl2][e]);
            Hb[base + (size_t)(c * LC + half * 16 + tl2) * HID_ + e] = f2bf(s);
        }
        __syncthreads();
    }

    // B_c -> SbufB bf16 in [e][d] layout (kv element j = kv2[j>>1][j&1])
    const size_t sbase = (size_t)(head * NC + c) * (D_ * D_);
    #pragma unroll
    for (int i = 0; i < 4; ++i) {
        ushort4 o = { f2bf(kv2[i * 2][0]),     f2bf(kv2[i * 2][1]),
                      f2bf(kv2[i * 2 + 1][0]), f2bf(kv2[i * 2 + 1][1]) };
        *(ushort4*)&SbufB[sbase + (size_t)lane * D_ + w * 16 + i * 4] = o;
    }
    if (lane < 16) Pbuf[(size_t)(head * NC + c) * D_ + dq] = pq;
    const unsigned short* qsl = &qs[0][0];
    *(short8*)&QAb[(size_t)(head * NC + c) * (LC * 64) + tid * 8] =
        *(const short8*)&qsl[tid * 8];
}

// ---------------------------------------------------------------------------
// Scan phase 2: combine across chunks. grid = 32 heads x 16 e-groups (512 blocks).
// Each thread owns one (e,d) element. ALL chunk loads prefetched to registers
// (independent, pipelined) before the serial FMA chain.
// ---------------------------------------------------------------------------
__global__ __launch_bounds__(256) void scan_combine(
    const unsigned short* __restrict__ SbufB,
    const float* __restrict__ Pbuf,
    unsigned short* __restrict__ SInitB)
{
    const int tid  = threadIdx.x;
    const int head = blockIdx.x >> 4;
    const int e    = (blockIdx.x & 15) * 4 + (tid >> 6);
    const int d    = tid & 63;

    unsigned short Bv[NC];
    float Pv[NC];
    #pragma unroll
    for (int ci = 0; ci < NC; ++ci) {
        const size_t sidx = (size_t)(head * NC + ci) * (D_ * D_) + (size_t)e * D_ + d;
        Bv[ci] = SbufB[sidx];
        Pv[ci] = Pbuf[(size_t)(head * NC + ci) * D_ + d];
    }

    float S = 0.f;
    #pragma unroll
    for (int ci = 0; ci < NC; ++ci) {
        const size_t sidx = (size_t)(head * NC + ci) * (D_ * D_) + (size_t)e * D_ + d;
        SInitB[sidx] = f2bf(S);
        S = Pv[ci] * S + bf2f(Bv[ci]);
    }
}

// ---------------------------------------------------------------------------
// Scan phase 3 (MFMA): h[t,e] += sum_d qa[t,d] * S_init[e,d]  per (head,chunk).
// One wave per (head,c); c==0 waves exit (S_init(0)=0).
// ---------------------------------------------------------------------------
__global__ __launch_bounds__(256) void scan_inter_mfma(
    const unsigned short* __restrict__ QAb,
    const unsigned short* __restrict__ SInitB,
    unsigned short* __restrict__ Hb)
{
    const int tid = threadIdx.x, w = tid >> 6, lane = tid & 63;
    const int wid  = blockIdx.x * 4 + w;      // 0..1023
    const int head = wid >> 5, c = wid & 31;
    if (c == 0) return;                       // wave-uniform: zero contribution
    const int n = head >> 4, h = head & 15;
    const int fr = lane & 15, fc = lane >> 4;

    const unsigned short* qa = QAb + (size_t)(head * NC + c) * (LC * 64);
    const unsigned short* sb = SInitB + (size_t)(head * NC + c) * (D_ * D_);

    short8 a[2][2], b[4][2];
    #pragma unroll
    for (int mi = 0; mi < 2; ++mi)
        #pragma unroll
        for (int ks = 0; ks < 2; ++ks)
            a[mi][ks] = *(const short8*)&qa[(mi * 16 + fr) * 64 + fc * 8 + ks * 32];
    #pragma unroll
    for (int ni = 0; ni < 4; ++ni)
        #pragma unroll
        for (int ks = 0; ks < 2; ++ks)
            b[ni][ks] = *(const short8*)&sb[(ni * 16 + fr) * 64 + fc * 8 + ks * 32];

    f32x4 acc[2][4] = {};
    #pragma unroll
    for (int mi = 0; mi < 2; ++mi)
        #pragma unroll
        for (int ni = 0; ni < 4; ++ni)
            #pragma unroll
            for (int ks = 0; ks < 2; ++ks)
                acc[mi][ni] = __builtin_amdgcn_mfma_f32_16x16x32_bf16(
                    a[mi][ks], b[ni][ks], acc[mi][ni], 0, 0, 0);

    #pragma unroll
    for (int mi = 0; mi < 2; ++mi)
        #pragma unroll
        for (int ni = 0; ni < 4; ++ni)
            #pragma unroll
            for (int r = 0; r < 4; ++r) {
                int t = c * LC + mi * 16 + fc * 4 + r;
                size_t g = ((size_t)n * T_ + t) * HID_ + h * 64 + ni * 16 + fr;
                Hb[g] = f2bf(bf2f(Hb[g]) + acc[mi][ni][r]);
            }
}

// ---------------------------------------------------------------------------
extern "C" void kernel_launch(void* const* d_in, const int* in_sizes, int n_in,
                              void* d_out, int out_size, void* d_ws, size_t ws_size,
                              hipStream_t stream)
{
    const float* x     = (const float*)d_in[0];
    const float* key_w = (const float*)d_in[1];
    const float* key_b = (const float*)d_in[2];
    const float* vq_w  = (const float*)d_in[3];
    const float* out_w = (const float*)d_in[4];
    const float* out_b = (const float*)d_in[5];
    float* out = (float*)d_out;

    const size_t MH = (size_t)MTOT * HID_;   // 2M elements
    unsigned short* Gb    = (unsigned short*)d_ws;                   // 4 MB
    unsigned short* Vb16  = Gb + MH;                                 // 4 MB
    unsigned short* Qb16  = Vb16 + MH;                               // 4 MB
    unsigned short* SbufB = Qb16 + MH;                               // 8 MB
    unsigned short* SInitB = SbufB + (size_t)NHEAD * NC * D_ * D_;   // 8 MB
    float* Pbuf = (float*)(SInitB + (size_t)NHEAD * NC * D_ * D_);   // 256 KB
    unsigned short* QAb = (unsigned short*)(Pbuf + (size_t)NHEAD * NC * D_);  // 4 MB
    unsigned short* Xb  = QAb + (size_t)NHEAD * NC * LC * D_;        // 4 MB
    unsigned short* Wb  = Xb + MH;                                   // 6 MB
    unsigned short* OWb = Wb + 3 * 1024 * 1024;                      // 2 MB
    unsigned short* Hb  = OWb + 1024 * 1024;                         // 4 MB

    cvt_all<<<3072, 256, 0, stream>>>(x, key_w, vq_w, out_w, Xb, Wb, OWb);
    gemm_qkv_mfma<<<dim3(24, 32), 256, 0, stream>>>(Xb, Wb, key_b, Gb, Vb16, Qb16);
    scan_phase1<<<NHEAD * NC, 256, 0, stream>>>(Gb, Vb16, Qb16, SbufB, Pbuf, QAb, Hb);
    scan_combine<<<NHEAD * 16, 256, 0, stream>>>(SbufB, Pbuf, SInitB);
    scan_inter_mfma<<<NHEAD * NC / 4, 256, 0, stream>>>(QAb, SInitB, Hb);
    gemm_out_mfma<<<dim3(16, 32), 256, 0, stream>>>(Hb, OWb, out_b, out);
}